// Round 9
// baseline (2826.169 us; speedup 1.0000x reference)
//
#include <hip/hip_runtime.h>

#define TT 512
#define BATCH 256
#define HH 1024

typedef _Float16 half4  __attribute__((ext_vector_type(4)));
typedef _Float16 half8  __attribute__((ext_vector_type(8)));
typedef float    floatx4 __attribute__((ext_vector_type(4)));
typedef unsigned uint4v  __attribute__((ext_vector_type(4)));
typedef unsigned long long u64;
typedef u64 u64x2 __attribute__((ext_vector_type(2)));

// Agent-scope (MALL-coherent) 8B ops — fallback path + init.
__device__ __forceinline__ u64 hload(const _Float16* p) {
    return __hip_atomic_load((const u64*)p, __ATOMIC_RELAXED, __HIP_MEMORY_SCOPE_AGENT);
}
__device__ __forceinline__ void hstore(_Float16* p, u64 v) {
    __hip_atomic_store((u64*)p, v, __ATOMIC_RELAXED, __HIP_MEMORY_SCOPE_AGENT);
}

// Operand-swapped step loop: D = W·h^T (D[j][b]). h is the MFMA B-operand,
// whose fragment is a contiguous 16B slice of one h row -> loaded DIRECTLY
// from L2 (volatile sc0, 64B-line coalesced). No LDS staging, no A-read
// conflicts. Waves = (jf-pair p, K-half kh); pair K-reduction via small
// conflict-free LDS exchange. h' written from registers (plain, writeback-L2);
// release = vmcnt(0)+barrier, then one sc0 flag store per producer.
// !FAST fallback: same structure via agent-scope 8B atomics + counter.
template<bool FAST>
__device__ __forceinline__ void run_steps(
    int bbq, int jb, int tid, int w, int l15, int lhi,
    const float* __restrict__ x0, const float* __restrict__ targets,
    float* __restrict__ out,
    _Float16* __restrict__ hbuf0, _Float16* __restrict__ hbuf1,
    unsigned* __restrict__ cnt, unsigned* __restrict__ flags,
    const half8 (&wfrag)[4][16],
    const float (&bias_r)[2][4], const float (&wih_r)[2][4],
    const float (&wout_r)[2][4], float bout,
    float* x_lds, floatx4* red, float* y_red)
{
    const int p   = w >> 1;          // jf-pair: cols [p*64, p*64+64)
    const int kh  = w & 1;           // K-half:  [kh*512, kh*512+512)
    const int kb0 = kh ? 2 : 0;      // kept blocks {kb0, kb0+1}
    const int sb0 = kh ? 0 : 2;      // sent blocks {sb0, sb0+1}
    const int l   = tid & 63;

    for (int s = 0; s < TT; ++s) {
        const _Float16* hs = (s & 1) ? hbuf1 : hbuf0;
        _Float16*       hd = (s & 1) ? hbuf0 : hbuf1;

        float xval = 0.f;
        if (tid < 16)
            xval = (s == 0) ? x0[bbq * 16 + tid]
                            : targets[(size_t)(s - 1) * BATCH + bbq * 16 + tid];

        // ---- wait for all 8 producers of the previous step ----
        if (tid == 0) {
            if (FAST) {
                const unsigned tgt = (unsigned)s;
                for (;;) {
                    uint4v a = *(volatile const uint4v*)&flags[bbq * 8];
                    uint4v b = *(volatile const uint4v*)&flags[bbq * 8 + 4];
                    unsigned m = a[0];
                    m = m < a[1] ? m : a[1]; m = m < a[2] ? m : a[2];
                    m = m < a[3] ? m : a[3]; m = m < b[0] ? m : b[0];
                    m = m < b[1] ? m : b[1]; m = m < b[2] ? m : b[2];
                    m = m < b[3] ? m : b[3];
                    if (m >= tgt) break;
                }
            } else {
                const unsigned tgt = 8u * (unsigned)(s + 1);
                while (__hip_atomic_load(&cnt[bbq], __ATOMIC_RELAXED,
                                         __HIP_MEMORY_SCOPE_AGENT) < tgt) {}
            }
        }
        if (tid < 16) x_lds[tid] = xval;
        __syncthreads();                                   // (A)
        __builtin_amdgcn_sched_barrier(0);

        // ---- B-frags: h^T straight from L2, 16B contiguous per lane ----
        // lane reads h[b = l15][kh*512 + t*32 + lhi*8 .. +8)
        const _Float16* hrow = hs + (size_t)(bbq * 16 + l15) * HH + kh * 512 + lhi * 8;
        floatx4 acc[4] = {{0,0,0,0},{0,0,0,0},{0,0,0,0},{0,0,0,0}};
        #pragma unroll
        for (int half = 0; half < 2; ++half) {             // 2 chunks of 8 -> bounded VGPR
            half8 bfrag[8];
            if (FAST) {
                #pragma unroll
                for (int t = 0; t < 8; ++t)
                    bfrag[t] = __builtin_bit_cast(half8,
                        *(volatile const u64x2*)(hrow + (half * 8 + t) * 32));
            } else {
                #pragma unroll
                for (int t = 0; t < 8; ++t) {
                    u64x2 v;
                    v[0] = hload(hrow + (half * 8 + t) * 32);
                    v[1] = hload(hrow + (half * 8 + t) * 32 + 4);
                    bfrag[t] = __builtin_bit_cast(half8, v);
                }
            }
            #pragma unroll
            for (int t = 0; t < 8; ++t) {
                #pragma unroll
                for (int b = 0; b < 4; ++b)
                    acc[b] = __builtin_amdgcn_mfma_f32_16x16x32_f16(
                        wfrag[b][half * 8 + t], bfrag[t], acc[b], 0, 0, 0);
            }
        }

        // ---- pair K-reduction: send 2 blocks via LDS (conflict-free) ----
        red[(p * 4 + sb0)     * 64 + l] = acc[sb0];
        red[(p * 4 + sb0 + 1) * 64 + l] = acc[sb0 + 1];
        __syncthreads();                                   // (C)
        floatx4 pre0 = acc[kb0]     + red[(p * 4 + kb0)     * 64 + l];
        floatx4 pre1 = acc[kb0 + 1] + red[(p * 4 + kb0 + 1) * 64 + l];

        // ---- epilogue: lane owns batch b=l15, j = base + {kept blk}*16 + lhi*4 + r
        const float xb = x_lds[l15];
        float ht[2][4];
        #pragma unroll
        for (int b2 = 0; b2 < 2; ++b2) {
            const floatx4 pre = b2 ? pre1 : pre0;
            #pragma unroll
            for (int r = 0; r < 4; ++r) {
                const float pp = pre[r] + bias_r[b2][r] + xb * wih_r[b2][r];
                const float ex = __expf(2.0f * pp);
                ht[b2][r] = 1.0f - 2.0f / (ex + 1.0f);
            }
        }

        // ---- h' store straight from registers: 2 x 8B per lane ----
        _Float16* hrd = hd + (size_t)(bbq * 16 + l15) * HH + jb * 128 + p * 64 + lhi * 4;
        #pragma unroll
        for (int b2 = 0; b2 < 2; ++b2) {
            half4 hv;
            hv[0] = (_Float16)ht[b2][0]; hv[1] = (_Float16)ht[b2][1];
            hv[2] = (_Float16)ht[b2][2]; hv[3] = (_Float16)ht[b2][3];
            if (FAST)
                *(half4*)(hrd + (kb0 + b2) * 16) = hv;     // plain: writeback L2
            else
                hstore(hrd + (kb0 + b2) * 16, __builtin_bit_cast(u64, hv));
        }

        // ---- y partial for batch l15 over this wave's 8 j's ----
        float yv = 0.f;
        #pragma unroll
        for (int b2 = 0; b2 < 2; ++b2)
            #pragma unroll
            for (int r = 0; r < 4; ++r)
                yv += ht[b2][r] * wout_r[b2][r];
        yv += __shfl_xor(yv, 16);
        yv += __shfl_xor(yv, 32);
        if (l < 16) y_red[w * 16 + l] = yv;

        asm volatile("s_waitcnt vmcnt(0)" ::: "memory");   // h' acked (per wave)
        __syncthreads();                                   // (D) all waves done
        if (tid == 0) {
            if (FAST)
                *(volatile unsigned*)&flags[bbq * 8 + jb] = (unsigned)(s + 1);
            else
                __hip_atomic_fetch_add(&cnt[bbq], 1u, __ATOMIC_RELAXED,
                                       __HIP_MEMORY_SCOPE_AGENT);
        }
        if (tid >= 64 && tid < 80) {
            const int b = tid - 64;
            const float y = y_red[b] + y_red[16 + b] + y_red[32 + b] + y_red[48 + b] + bout;
            atomicAdd(&out[(size_t)s * BATCH + bbq * 16 + b], y);
        }
    }
}

// Grid: 128 wgs, 256 threads. bbq = wg&15, jb = wg>>4 -> group members share
// blockIdx mod 8 -> same XCD under round-robin. Colocation VERIFIED at runtime
// (HW_REG_XCC_ID exchange); L2-local fast path only when verified.
__global__ __launch_bounds__(256, 1)
void rnn_persistent(const float* __restrict__ x0,
                    const float* __restrict__ hidden0,
                    const float* __restrict__ targets,
                    const float* __restrict__ W_ih,
                    const float* __restrict__ W_hh,
                    const float* __restrict__ b_ih,
                    const float* __restrict__ b_hh,
                    const float* __restrict__ W_out,
                    const float* __restrict__ b_out,
                    float*       __restrict__ out,     // pre-zeroed
                    _Float16*    __restrict__ hbuf0,
                    _Float16*    __restrict__ hbuf1,
                    unsigned*    __restrict__ cnt,     // [16] agent counters
                    unsigned*    __restrict__ flags,   // [16][8] step flags
                    unsigned*    __restrict__ xcds)    // [128] XCC ids
{
    const int wg  = blockIdx.x;
    const int bbq = wg & 15;
    const int jb  = wg >> 4;
    const int tid = threadIdx.x;
    const int w   = tid >> 6;
    const int l   = tid & 63;
    const int l15 = l & 15;
    const int lhi = l >> 4;
    const int p   = w >> 1;
    const int kh  = w & 1;
    const int kb0 = kh ? 2 : 0;

    __shared__ __align__(16) float   x_lds[16];
    __shared__ __align__(16) floatx4 red[2 * 4 * 64];    // 8 KB pair exchange
    __shared__ __align__(16) float   y_red[4 * 16];
    __shared__            int        fastflag;

    unsigned xcc;
    asm volatile("s_getreg_b32 %0, hwreg(HW_REG_XCC_ID)" : "=s"(xcc));

    // ---- one-time: W_hh A-frags. block b: rows jb*128+p*64+b*16+l15,
    //      k = kh*512 + t*32 + lhi*8  (f16, 256 VGPRs) ----
    half8 wfrag[4][16];
    #pragma unroll
    for (int b = 0; b < 4; ++b) {
        const float* wr = W_hh + (size_t)(jb * 128 + p * 64 + b * 16 + l15) * HH
                         + kh * 512 + lhi * 8;
        #pragma unroll
        for (int t = 0; t < 16; ++t) {
            floatx4 lo = *(const floatx4*)(wr + t * 32);
            floatx4 hi = *(const floatx4*)(wr + t * 32 + 4);
            half8 f;
            f[0]=(_Float16)lo[0]; f[1]=(_Float16)lo[1]; f[2]=(_Float16)lo[2]; f[3]=(_Float16)lo[3];
            f[4]=(_Float16)hi[0]; f[5]=(_Float16)hi[1]; f[6]=(_Float16)hi[2]; f[7]=(_Float16)hi[3];
            wfrag[b][t] = f;
        }
    }

    // per-lane epilogue constants for the 2 KEPT blocks
    float bias_r[2][4], wih_r[2][4], wout_r[2][4];
    #pragma unroll
    for (int b2 = 0; b2 < 2; ++b2)
        #pragma unroll
        for (int r = 0; r < 4; ++r) {
            const int j = jb * 128 + p * 64 + (kb0 + b2) * 16 + lhi * 4 + r;
            bias_r[b2][r] = b_ih[j] + b_hh[j];
            wih_r[b2][r]  = W_ih[j];
            wout_r[b2][r] = W_out[j];
        }
    const float bout = (jb == 0) ? b_out[0] : 0.f;

    // ---- init: fp32 hidden -> f16 hbuf0 (agent stores) + publish XCC id ----
    #pragma unroll
    for (int c = 0; c < 2; ++c) {
        const int q   = tid + c * 256;
        const int row = q >> 5, cc = q & 31;
        const float* s = hidden0 + (size_t)(bbq * 16 + row) * HH + jb * 128 + cc * 4;
        floatx4 f4 = *(const floatx4*)s;
        half4 h4;
        h4[0]=(_Float16)f4[0]; h4[1]=(_Float16)f4[1]; h4[2]=(_Float16)f4[2]; h4[3]=(_Float16)f4[3];
        hstore(hbuf0 + (size_t)(bbq * 16 + row) * HH + jb * 128 + cc * 4,
               __builtin_bit_cast(u64, h4));
    }
    if (tid == 0)
        __hip_atomic_store(&xcds[wg], xcc, __ATOMIC_RELAXED, __HIP_MEMORY_SCOPE_AGENT);
    asm volatile("s_waitcnt vmcnt(0)" ::: "memory");
    __syncthreads();
    if (tid == 0)
        __hip_atomic_fetch_add(&cnt[bbq], 1u, __ATOMIC_RELAXED, __HIP_MEMORY_SCOPE_AGENT);

    // ---- verdict: all 8 group members on one XCD? ----
    if (tid == 0) {
        while (__hip_atomic_load(&cnt[bbq], __ATOMIC_RELAXED,
                                 __HIP_MEMORY_SCOPE_AGENT) < 8u) {}
    }
    __syncthreads();
    if (tid < 64) {
        unsigned v = 0;
        if (l < 8)
            v = __hip_atomic_load(&xcds[(l << 4) + bbq], __ATOMIC_RELAXED,
                                  __HIP_MEMORY_SCOPE_AGENT);
        const unsigned v0 = __shfl(v, 0);
        const bool ok = (l >= 8) || (v == v0);
        const unsigned long long m = __ballot(ok);
        if (tid == 0) fastflag = (m == ~0ull) ? 1 : 0;
    }
    __syncthreads();
    const bool fast = (fastflag != 0);

    if (fast)
        run_steps<true >(bbq, jb, tid, w, l15, lhi, x0, targets, out,
                         hbuf0, hbuf1, cnt, flags, wfrag,
                         bias_r, wih_r, wout_r, bout, x_lds, red, y_red);
    else
        run_steps<false>(bbq, jb, tid, w, l15, lhi, x0, targets, out,
                         hbuf0, hbuf1, cnt, flags, wfrag,
                         bias_r, wih_r, wout_r, bout, x_lds, red, y_red);
}

extern "C" void kernel_launch(void* const* d_in, const int* in_sizes, int n_in,
                              void* d_out, int out_size, void* d_ws, size_t ws_size,
                              hipStream_t stream)
{
    const float* x0      = (const float*)d_in[0];
    const float* hidden0 = (const float*)d_in[1];
    const float* targets = (const float*)d_in[2];
    const float* W_ih    = (const float*)d_in[3];
    const float* W_hh    = (const float*)d_in[4];
    const float* b_ih    = (const float*)d_in[5];
    const float* b_hh    = (const float*)d_in[6];
    const float* W_out   = (const float*)d_in[7];
    const float* b_out   = (const float*)d_in[8];
    float* out = (float*)d_out;

    char* ws = (char*)d_ws;
    unsigned* cnt   = (unsigned*)ws;                          // [16]     @0
    unsigned* flags = (unsigned*)(ws + 256);                  // [16][8]  @256
    unsigned* xcds  = (unsigned*)(ws + 1024);                 // [128]    @1024
    _Float16* hbuf0 = (_Float16*)(ws + 4096);                 // 512 KB
    _Float16* hbuf1 = (_Float16*)(ws + 4096 + 512 * 1024);    // 512 KB

    hipMemsetAsync(ws, 0, 4096, stream);
    hipMemsetAsync(d_out, 0, (size_t)out_size * sizeof(float), stream);

    rnn_persistent<<<128, 256, 0, stream>>>(x0, hidden0, targets, W_ih, W_hh,
                                            b_ih, b_hh, W_out, b_out,
                                            out, hbuf0, hbuf1, cnt, flags, xcds);
}

// Round 10
// 2636.762 us; speedup vs baseline: 1.0718x; 1.0718x over previous
//
#include <hip/hip_runtime.h>

#define TT 512
#define BATCH 256
#define HH 1024

typedef _Float16 half4  __attribute__((ext_vector_type(4)));
typedef _Float16 half8  __attribute__((ext_vector_type(8)));
typedef float    floatx4 __attribute__((ext_vector_type(4)));
typedef unsigned uint4v  __attribute__((ext_vector_type(4)));
typedef unsigned long long u64;
typedef u64 u64x2 __attribute__((ext_vector_type(2)));

#define ROWB 2064   // padded LDS row stride: 129 x 16B -> slot(r,c)=(r+c)%8, conflict-free

// Agent-scope (MALL-coherent) 8B ops — fallback path + init.
__device__ __forceinline__ u64 hload(const _Float16* p) {
    return __hip_atomic_load((const u64*)p, __ATOMIC_RELAXED, __HIP_MEMORY_SCOPE_AGENT);
}
__device__ __forceinline__ void hstore(_Float16* p, u64 v) {
    __hip_atomic_store((u64*)p, v, __ATOMIC_RELAXED, __HIP_MEMORY_SCOPE_AGENT);
}

// Step loop, operand-swapped MFMA (D = W·h^T), 2x2 wave split (jf-pair p,
// K-half kh). h-tile staged ONCE per wg into padding-deconflicted LDS
// (coalesced L2 reads); each wave reads only its 16KB K-half from LDS.
// Pair K-reduction via conflict-free LDS exchange. h' stored from registers
// (plain writeback-L2); release = vmcnt(0)+barrier+sc0 flag. !FAST fallback:
// same structure via agent-scope atomics + counter.
template<bool FAST>
__device__ __forceinline__ void run_steps(
    int bbq, int jb, int tid, int w, int l15, int lhi,
    const float* __restrict__ x0, const float* __restrict__ targets,
    float* __restrict__ out,
    _Float16* __restrict__ hbuf0, _Float16* __restrict__ hbuf1,
    unsigned* __restrict__ cnt, unsigned* __restrict__ flags,
    const half8 (&wfrag)[4][16],
    const float (&bias_r)[2][4], const float (&wih_r)[2][4],
    const float (&wout_r)[2][4], float bout,
    float* x_lds, floatx4* red, float* y_red, char* hstage_b)
{
    const int p   = w >> 1;          // jf-pair: cols [p*64, p*64+64)
    const int kh  = w & 1;           // K-half:  [kh*512, kh*512+512)
    const int kb0 = kh ? 2 : 0;      // kept blocks {kb0, kb0+1}
    const int sb0 = kh ? 0 : 2;      // sent blocks {sb0, sb0+1}
    const int l   = tid & 63;
    const int bbase = l15 * ROWB + kh * 1024 + lhi * 16;  // B-frag LDS base

    for (int s = 0; s < TT; ++s) {
        const _Float16* hs = (s & 1) ? hbuf1 : hbuf0;
        _Float16*       hd = (s & 1) ? hbuf0 : hbuf1;

        float xval = 0.f;
        if (tid < 16)
            xval = (s == 0) ? x0[bbq * 16 + tid]
                            : targets[(size_t)(s - 1) * BATCH + bbq * 16 + tid];

        // ---- wait for all 8 producers of the previous step ----
        if (tid == 0) {
            if (FAST) {
                const unsigned tgt = (unsigned)s;
                for (;;) {
                    uint4v a = *(volatile const uint4v*)&flags[bbq * 8];
                    uint4v b = *(volatile const uint4v*)&flags[bbq * 8 + 4];
                    unsigned m = a[0];
                    m = m < a[1] ? m : a[1]; m = m < a[2] ? m : a[2];
                    m = m < a[3] ? m : a[3]; m = m < b[0] ? m : b[0];
                    m = m < b[1] ? m : b[1]; m = m < b[2] ? m : b[2];
                    m = m < b[3] ? m : b[3];
                    if (m >= tgt) break;
                }
            } else {
                const unsigned tgt = 8u * (unsigned)(s + 1);
                while (__hip_atomic_load(&cnt[bbq], __ATOMIC_RELAXED,
                                         __HIP_MEMORY_SCOPE_AGENT) < tgt) {}
            }
        }
        if (tid < 16) x_lds[tid] = xval;
        __syncthreads();                                   // (A)
        __builtin_amdgcn_sched_barrier(0);

        // ---- stage group h-tile (16 x 1024 f16 = 32 KB) into padded LDS ----
        {
            u64x2 sv[8];
            if (FAST) {
                const char* gsrc = (const char*)(hs + (size_t)bbq * 16 * HH);
                #pragma unroll
                for (int i = 0; i < 8; ++i) {
                    const int c = tid + i * 256;           // 2048 x 16B chunks
                    sv[i] = *(volatile const u64x2*)(gsrc + (c >> 7) * 2048 + (c & 127) * 16);
                }
            } else {
                const _Float16* sb = hs + (size_t)bbq * 16 * HH;
                #pragma unroll
                for (int i = 0; i < 8; ++i) {
                    const int c = tid + i * 256;
                    const _Float16* q = sb + (c >> 7) * HH + (c & 127) * 8;
                    u64x2 v; v[0] = hload(q); v[1] = hload(q + 4);
                    sv[i] = v;
                }
            }
            __builtin_amdgcn_sched_barrier(0);             // all loads issue first
            #pragma unroll
            for (int i = 0; i < 8; ++i) {
                const int c = tid + i * 256;
                *(u64x2*)(hstage_b + (c >> 7) * ROWB + (c & 127) * 16) = sv[i];
            }
        }
        __syncthreads();                                   // (B)

        // ---- MFMA from LDS: wave (p,kh) -> 4 col-blocks x K/2 ----
        floatx4 acc[4] = {{0,0,0,0},{0,0,0,0},{0,0,0,0},{0,0,0,0}};
        #pragma unroll
        for (int half = 0; half < 2; ++half) {             // 2 chunks of 8
            half8 bfrag[8];
            #pragma unroll
            for (int t = 0; t < 8; ++t)
                bfrag[t] = *(const half8*)(hstage_b + bbase + (half * 8 + t) * 64);
            #pragma unroll
            for (int t = 0; t < 8; ++t) {
                #pragma unroll
                for (int b = 0; b < 4; ++b)
                    acc[b] = __builtin_amdgcn_mfma_f32_16x16x32_f16(
                        wfrag[b][half * 8 + t], bfrag[t], acc[b], 0, 0, 0);
            }
        }

        // ---- pair K-reduction: send 2 blocks via LDS (conflict-free) ----
        red[(p * 4 + sb0)     * 64 + l] = acc[sb0];
        red[(p * 4 + sb0 + 1) * 64 + l] = acc[sb0 + 1];
        __syncthreads();                                   // (C)
        floatx4 pre0 = acc[kb0]     + red[(p * 4 + kb0)     * 64 + l];
        floatx4 pre1 = acc[kb0 + 1] + red[(p * 4 + kb0 + 1) * 64 + l];

        // ---- epilogue: lane owns batch b=l15, j = base + kept-blk*16 + lhi*4 + r
        const float xb = x_lds[l15];
        float ht[2][4];
        #pragma unroll
        for (int b2 = 0; b2 < 2; ++b2) {
            const floatx4 pre = b2 ? pre1 : pre0;
            #pragma unroll
            for (int r = 0; r < 4; ++r) {
                const float pp = pre[r] + bias_r[b2][r] + xb * wih_r[b2][r];
                const float ex = __expf(2.0f * pp);
                ht[b2][r] = 1.0f - 2.0f / (ex + 1.0f);
            }
        }

        // ---- h' store straight from registers: 2 x 8B per lane ----
        _Float16* hrd = hd + (size_t)(bbq * 16 + l15) * HH + jb * 128 + p * 64 + lhi * 4;
        #pragma unroll
        for (int b2 = 0; b2 < 2; ++b2) {
            half4 hv;
            hv[0] = (_Float16)ht[b2][0]; hv[1] = (_Float16)ht[b2][1];
            hv[2] = (_Float16)ht[b2][2]; hv[3] = (_Float16)ht[b2][3];
            if (FAST)
                *(half4*)(hrd + (kb0 + b2) * 16) = hv;     // plain: writeback L2
            else
                hstore(hrd + (kb0 + b2) * 16, __builtin_bit_cast(u64, hv));
        }

        // ---- y partial for batch l15 over this wave's 8 j's ----
        float yv = 0.f;
        #pragma unroll
        for (int b2 = 0; b2 < 2; ++b2)
            #pragma unroll
            for (int r = 0; r < 4; ++r)
                yv += ht[b2][r] * wout_r[b2][r];
        yv += __shfl_xor(yv, 16);
        yv += __shfl_xor(yv, 32);
        if (l < 16) y_red[w * 16 + l] = yv;

        asm volatile("s_waitcnt vmcnt(0)" ::: "memory");   // h' acked (per wave)
        __syncthreads();                                   // (D) all waves done
        if (tid == 0) {
            if (FAST)
                *(volatile unsigned*)&flags[bbq * 8 + jb] = (unsigned)(s + 1);
            else
                __hip_atomic_fetch_add(&cnt[bbq], 1u, __ATOMIC_RELAXED,
                                       __HIP_MEMORY_SCOPE_AGENT);
        }
        if (tid >= 64 && tid < 80) {
            const int b = tid - 64;
            const float y = y_red[b] + y_red[16 + b] + y_red[32 + b] + y_red[48 + b] + bout;
            atomicAdd(&out[(size_t)s * BATCH + bbq * 16 + b], y);
        }
    }
}

// Grid: 128 wgs, 256 threads. bbq = wg&15, jb = wg>>4 -> group members share
// blockIdx mod 8 -> same XCD under round-robin. Colocation VERIFIED at runtime
// (HW_REG_XCC_ID exchange); L2-local fast path only when verified.
__global__ __launch_bounds__(256, 1)
void rnn_persistent(const float* __restrict__ x0,
                    const float* __restrict__ hidden0,
                    const float* __restrict__ targets,
                    const float* __restrict__ W_ih,
                    const float* __restrict__ W_hh,
                    const float* __restrict__ b_ih,
                    const float* __restrict__ b_hh,
                    const float* __restrict__ W_out,
                    const float* __restrict__ b_out,
                    float*       __restrict__ out,     // pre-zeroed
                    _Float16*    __restrict__ hbuf0,
                    _Float16*    __restrict__ hbuf1,
                    unsigned*    __restrict__ cnt,     // [16] agent counters
                    unsigned*    __restrict__ flags,   // [16][8] step flags
                    unsigned*    __restrict__ xcds)    // [128] XCC ids
{
    const int wg  = blockIdx.x;
    const int bbq = wg & 15;
    const int jb  = wg >> 4;
    const int tid = threadIdx.x;
    const int w   = tid >> 6;
    const int l   = tid & 63;
    const int l15 = l & 15;
    const int lhi = l >> 4;
    const int p   = w >> 1;
    const int kh  = w & 1;
    const int kb0 = kh ? 2 : 0;

    __shared__ __align__(16) char    hstage_raw[16 * ROWB];  // 33 KB padded tile
    __shared__ __align__(16) floatx4 red[2 * 4 * 64];        // 8 KB pair exchange
    __shared__ __align__(16) float   x_lds[16];
    __shared__ __align__(16) float   y_red[4 * 16];
    __shared__            int        fastflag;

    unsigned xcc;
    asm volatile("s_getreg_b32 %0, hwreg(HW_REG_XCC_ID)" : "=s"(xcc));

    // ---- one-time: W_hh A-frags. block b: rows jb*128+p*64+b*16+l15,
    //      k = kh*512 + t*32 + lhi*8  (f16, 256 VGPRs) ----
    half8 wfrag[4][16];
    #pragma unroll
    for (int b = 0; b < 4; ++b) {
        const float* wr = W_hh + (size_t)(jb * 128 + p * 64 + b * 16 + l15) * HH
                         + kh * 512 + lhi * 8;
        #pragma unroll
        for (int t = 0; t < 16; ++t) {
            floatx4 lo = *(const floatx4*)(wr + t * 32);
            floatx4 hi = *(const floatx4*)(wr + t * 32 + 4);
            half8 f;
            f[0]=(_Float16)lo[0]; f[1]=(_Float16)lo[1]; f[2]=(_Float16)lo[2]; f[3]=(_Float16)lo[3];
            f[4]=(_Float16)hi[0]; f[5]=(_Float16)hi[1]; f[6]=(_Float16)hi[2]; f[7]=(_Float16)hi[3];
            wfrag[b][t] = f;
        }
    }

    // per-lane epilogue constants for the 2 KEPT blocks
    float bias_r[2][4], wih_r[2][4], wout_r[2][4];
    #pragma unroll
    for (int b2 = 0; b2 < 2; ++b2)
        #pragma unroll
        for (int r = 0; r < 4; ++r) {
            const int j = jb * 128 + p * 64 + (kb0 + b2) * 16 + lhi * 4 + r;
            bias_r[b2][r] = b_ih[j] + b_hh[j];
            wih_r[b2][r]  = W_ih[j];
            wout_r[b2][r] = W_out[j];
        }
    const float bout = (jb == 0) ? b_out[0] : 0.f;

    // ---- init: fp32 hidden -> f16 hbuf0 (agent stores) + publish XCC id ----
    #pragma unroll
    for (int c = 0; c < 2; ++c) {
        const int q   = tid + c * 256;
        const int row = q >> 5, cc = q & 31;
        const float* s = hidden0 + (size_t)(bbq * 16 + row) * HH + jb * 128 + cc * 4;
        floatx4 f4 = *(const floatx4*)s;
        half4 h4;
        h4[0]=(_Float16)f4[0]; h4[1]=(_Float16)f4[1]; h4[2]=(_Float16)f4[2]; h4[3]=(_Float16)f4[3];
        hstore(hbuf0 + (size_t)(bbq * 16 + row) * HH + jb * 128 + cc * 4,
               __builtin_bit_cast(u64, h4));
    }
    if (tid == 0)
        __hip_atomic_store(&xcds[wg], xcc, __ATOMIC_RELAXED, __HIP_MEMORY_SCOPE_AGENT);
    asm volatile("s_waitcnt vmcnt(0)" ::: "memory");
    __syncthreads();
    if (tid == 0)
        __hip_atomic_fetch_add(&cnt[bbq], 1u, __ATOMIC_RELAXED, __HIP_MEMORY_SCOPE_AGENT);

    // ---- verdict: all 8 group members on one XCD? ----
    if (tid == 0) {
        while (__hip_atomic_load(&cnt[bbq], __ATOMIC_RELAXED,
                                 __HIP_MEMORY_SCOPE_AGENT) < 8u) {}
    }
    __syncthreads();
    if (tid < 64) {
        unsigned v = 0;
        if (l < 8)
            v = __hip_atomic_load(&xcds[(l << 4) + bbq], __ATOMIC_RELAXED,
                                  __HIP_MEMORY_SCOPE_AGENT);
        const unsigned v0 = __shfl(v, 0);
        const bool ok = (l >= 8) || (v == v0);
        const unsigned long long m = __ballot(ok);
        if (tid == 0) fastflag = (m == ~0ull) ? 1 : 0;
    }
    __syncthreads();
    const bool fast = (fastflag != 0);

    if (fast)
        run_steps<true >(bbq, jb, tid, w, l15, lhi, x0, targets, out,
                         hbuf0, hbuf1, cnt, flags, wfrag,
                         bias_r, wih_r, wout_r, bout, x_lds, red, y_red, hstage_raw);
    else
        run_steps<false>(bbq, jb, tid, w, l15, lhi, x0, targets, out,
                         hbuf0, hbuf1, cnt, flags, wfrag,
                         bias_r, wih_r, wout_r, bout, x_lds, red, y_red, hstage_raw);
}

extern "C" void kernel_launch(void* const* d_in, const int* in_sizes, int n_in,
                              void* d_out, int out_size, void* d_ws, size_t ws_size,
                              hipStream_t stream)
{
    const float* x0      = (const float*)d_in[0];
    const float* hidden0 = (const float*)d_in[1];
    const float* targets = (const float*)d_in[2];
    const float* W_ih    = (const float*)d_in[3];
    const float* W_hh    = (const float*)d_in[4];
    const float* b_ih    = (const float*)d_in[5];
    const float* b_hh    = (const float*)d_in[6];
    const float* W_out   = (const float*)d_in[7];
    const float* b_out   = (const float*)d_in[8];
    float* out = (float*)d_out;

    char* ws = (char*)d_ws;
    unsigned* cnt   = (unsigned*)ws;                          // [16]     @0
    unsigned* flags = (unsigned*)(ws + 256);                  // [16][8]  @256
    unsigned* xcds  = (unsigned*)(ws + 1024);                 // [128]    @1024
    _Float16* hbuf0 = (_Float16*)(ws + 4096);                 // 512 KB
    _Float16* hbuf1 = (_Float16*)(ws + 4096 + 512 * 1024);    // 512 KB

    hipMemsetAsync(ws, 0, 4096, stream);
    hipMemsetAsync(d_out, 0, (size_t)out_size * sizeof(float), stream);

    rnn_persistent<<<128, 256, 0, stream>>>(x0, hidden0, targets, W_ih, W_hh,
                                            b_ih, b_hh, W_out, b_out,
                                            out, hbuf0, hbuf1, cnt, flags, xcds);
}

// Round 11
// 2333.256 us; speedup vs baseline: 1.2113x; 1.1301x over previous
//
#include <hip/hip_runtime.h>

#define TT 512
#define BATCH 256
#define HH 1024

typedef _Float16 half4  __attribute__((ext_vector_type(4)));
typedef _Float16 half8  __attribute__((ext_vector_type(8)));
typedef float    floatx4 __attribute__((ext_vector_type(4)));
typedef unsigned uint4v  __attribute__((ext_vector_type(4)));
typedef unsigned long long u64;
typedef u64 u64x2 __attribute__((ext_vector_type(2)));

#define ROWB 2064   // padded LDS row stride (129 x 16B)

// Agent-scope (MALL-coherent) 8B ops — fallback path + init.
__device__ __forceinline__ u64 hload(const _Float16* p) {
    return __hip_atomic_load((const u64*)p, __ATOMIC_RELAXED, __HIP_MEMORY_SCOPE_AGENT);
}
__device__ __forceinline__ void hstore(_Float16* p, u64 v) {
    __hip_atomic_store((u64*)p, v, __ATOMIC_RELAXED, __HIP_MEMORY_SCOPE_AGENT);
}

// Step loop, operand-swapped MFMA (D = W·h^T), 2x2 wave split.
// FAST path h exchange (group verified on ONE XCD):
//   producers: PLAIN stores (write-through L1 -> L2) + vmcnt(0) + sc0 flag.
//   consumers: poll sc0 flags -> barrier -> `buffer_inv` (vL1-only inv) ->
//              PLAIN cached b128 loads (normal L1/L2 path — avoids the
//              ~34 req/cy chip-wide coherent-request tax that bounded R4-R10).
// !FAST: agent-scope 8B atomics via MALL + counter (placement-agnostic).
template<bool FAST>
__device__ __forceinline__ void run_steps(
    int bbq, int jb, int tid, int w, int l15, int lhi,
    const float* __restrict__ x0, const float* __restrict__ targets,
    float* __restrict__ out,
    _Float16* __restrict__ hbuf0, _Float16* __restrict__ hbuf1,
    unsigned* __restrict__ cnt, unsigned* __restrict__ flags,
    const half8 (&wfrag)[4][16],
    const float (&bias_r)[2][4], const float (&wih_r)[2][4],
    const float (&wout_r)[2][4], float bout,
    float* x_lds, floatx4* red, float* y_red, char* hstage_b)
{
    const int p   = w >> 1;          // jf-pair: cols [p*64, p*64+64)
    const int kh  = w & 1;           // K-half:  [kh*512, kh*512+512)
    const int kb0 = kh ? 2 : 0;      // kept blocks {kb0, kb0+1}
    const int sb0 = kh ? 0 : 2;      // sent blocks {sb0, sb0+1}
    const int l   = tid & 63;
    const int bbase = l15 * ROWB + kh * 1024 + lhi * 16;  // B-frag LDS base

    for (int s = 0; s < TT; ++s) {
        const _Float16* hs = (s & 1) ? hbuf1 : hbuf0;
        _Float16*       hd = (s & 1) ? hbuf0 : hbuf1;

        float xval = 0.f;
        if (tid < 16)
            xval = (s == 0) ? x0[bbq * 16 + tid]
                            : targets[(size_t)(s - 1) * BATCH + bbq * 16 + tid];

        // ---- wait for all 8 producers of the previous step ----
        if (tid == 0) {
            if (FAST) {
                const unsigned tgt = (unsigned)s;
                for (;;) {
                    uint4v a = *(volatile const uint4v*)&flags[bbq * 8];
                    uint4v b = *(volatile const uint4v*)&flags[bbq * 8 + 4];
                    unsigned m = a[0];
                    m = m < a[1] ? m : a[1]; m = m < a[2] ? m : a[2];
                    m = m < a[3] ? m : a[3]; m = m < b[0] ? m : b[0];
                    m = m < b[1] ? m : b[1]; m = m < b[2] ? m : b[2];
                    m = m < b[3] ? m : b[3];
                    if (m >= tgt) break;
                }
            } else {
                const unsigned tgt = 8u * (unsigned)(s + 1);
                while (__hip_atomic_load(&cnt[bbq], __ATOMIC_RELAXED,
                                         __HIP_MEMORY_SCOPE_AGENT) < tgt) {}
            }
        }
        if (tid < 16) x_lds[tid] = xval;
        __syncthreads();                                   // (A)
        __builtin_amdgcn_sched_barrier(0);

        // ---- stage group h-tile (16 x 1024 f16 = 32 KB) into padded LDS ----
        {
            u64x2 sv[8];
            if (FAST) {
                // vL1-only invalidate, then PLAIN cached loads (L2-served).
                asm volatile("s_waitcnt vmcnt(0)\n\tbuffer_inv" ::: "memory");
                __builtin_amdgcn_sched_barrier(0);
                const char* gsrc = (const char*)(hs + (size_t)bbq * 16 * HH);
                #pragma unroll
                for (int i = 0; i < 8; ++i) {
                    const int c = tid + i * 256;           // 2048 x 16B chunks
                    sv[i] = *(const u64x2*)(gsrc + (c >> 7) * 2048 + (c & 127) * 16);
                }
            } else {
                const _Float16* sb = hs + (size_t)bbq * 16 * HH;
                #pragma unroll
                for (int i = 0; i < 8; ++i) {
                    const int c = tid + i * 256;
                    const _Float16* q = sb + (c >> 7) * HH + (c & 127) * 8;
                    u64x2 v; v[0] = hload(q); v[1] = hload(q + 4);
                    sv[i] = v;
                }
            }
            __builtin_amdgcn_sched_barrier(0);             // all loads issue first
            #pragma unroll
            for (int i = 0; i < 8; ++i) {
                const int c = tid + i * 256;
                *(u64x2*)(hstage_b + (c >> 7) * ROWB + (c & 127) * 16) = sv[i];
            }
        }
        __syncthreads();                                   // (B)

        // ---- MFMA from LDS: wave (p,kh) -> 4 col-blocks x K/2 ----
        floatx4 acc[4] = {{0,0,0,0},{0,0,0,0},{0,0,0,0},{0,0,0,0}};
        #pragma unroll
        for (int half = 0; half < 2; ++half) {             // 2 chunks of 8
            half8 bfrag[8];
            #pragma unroll
            for (int t = 0; t < 8; ++t)
                bfrag[t] = *(const half8*)(hstage_b + bbase + (half * 8 + t) * 64);
            #pragma unroll
            for (int t = 0; t < 8; ++t) {
                #pragma unroll
                for (int b = 0; b < 4; ++b)
                    acc[b] = __builtin_amdgcn_mfma_f32_16x16x32_f16(
                        wfrag[b][half * 8 + t], bfrag[t], acc[b], 0, 0, 0);
            }
        }

        // ---- pair K-reduction: send 2 blocks via LDS (conflict-free) ----
        red[(p * 4 + sb0)     * 64 + l] = acc[sb0];
        red[(p * 4 + sb0 + 1) * 64 + l] = acc[sb0 + 1];
        __syncthreads();                                   // (C)
        floatx4 pre0 = acc[kb0]     + red[(p * 4 + kb0)     * 64 + l];
        floatx4 pre1 = acc[kb0 + 1] + red[(p * 4 + kb0 + 1) * 64 + l];

        // ---- epilogue: lane owns batch b=l15, j = base + kept-blk*16 + lhi*4 + r
        const float xb = x_lds[l15];
        float ht[2][4];
        #pragma unroll
        for (int b2 = 0; b2 < 2; ++b2) {
            const floatx4 pre = b2 ? pre1 : pre0;
            #pragma unroll
            for (int r = 0; r < 4; ++r) {
                const float pp = pre[r] + bias_r[b2][r] + xb * wih_r[b2][r];
                const float ex = __expf(2.0f * pp);
                ht[b2][r] = 1.0f - 2.0f / (ex + 1.0f);
            }
        }

        // ---- h' store straight from registers: 2 x 8B per lane ----
        _Float16* hrd = hd + (size_t)(bbq * 16 + l15) * HH + jb * 128 + p * 64 + lhi * 4;
        #pragma unroll
        for (int b2 = 0; b2 < 2; ++b2) {
            half4 hv;
            hv[0] = (_Float16)ht[b2][0]; hv[1] = (_Float16)ht[b2][1];
            hv[2] = (_Float16)ht[b2][2]; hv[3] = (_Float16)ht[b2][3];
            if (FAST)
                *(half4*)(hrd + (kb0 + b2) * 16) = hv;     // plain: write-through to L2
            else
                hstore(hrd + (kb0 + b2) * 16, __builtin_bit_cast(u64, hv));
        }

        // ---- y partial for batch l15 over this wave's 8 j's ----
        float yv = 0.f;
        #pragma unroll
        for (int b2 = 0; b2 < 2; ++b2)
            #pragma unroll
            for (int r = 0; r < 4; ++r)
                yv += ht[b2][r] * wout_r[b2][r];
        yv += __shfl_xor(yv, 16);
        yv += __shfl_xor(yv, 32);
        if (l < 16) y_red[w * 16 + l] = yv;

        asm volatile("s_waitcnt vmcnt(0)" ::: "memory");   // h' acked in L2 (per wave)
        __syncthreads();                                   // (D) all waves done
        if (tid == 0) {
            if (FAST)
                *(volatile unsigned*)&flags[bbq * 8 + jb] = (unsigned)(s + 1);
            else
                __hip_atomic_fetch_add(&cnt[bbq], 1u, __ATOMIC_RELAXED,
                                       __HIP_MEMORY_SCOPE_AGENT);
        }
        if (tid >= 64 && tid < 80) {
            const int b = tid - 64;
            const float y = y_red[b] + y_red[16 + b] + y_red[32 + b] + y_red[48 + b] + bout;
            atomicAdd(&out[(size_t)s * BATCH + bbq * 16 + b], y);
        }
    }
}

// Grid: 128 wgs, 256 threads. bbq = wg&15, jb = wg>>4 -> group members share
// blockIdx mod 8 -> same XCD under round-robin. Colocation VERIFIED at runtime
// (HW_REG_XCC_ID exchange); L2-local fast path only when verified.
__global__ __launch_bounds__(256, 1)
void rnn_persistent(const float* __restrict__ x0,
                    const float* __restrict__ hidden0,
                    const float* __restrict__ targets,
                    const float* __restrict__ W_ih,
                    const float* __restrict__ W_hh,
                    const float* __restrict__ b_ih,
                    const float* __restrict__ b_hh,
                    const float* __restrict__ W_out,
                    const float* __restrict__ b_out,
                    float*       __restrict__ out,     // pre-zeroed
                    _Float16*    __restrict__ hbuf0,
                    _Float16*    __restrict__ hbuf1,
                    unsigned*    __restrict__ cnt,     // [16] agent counters
                    unsigned*    __restrict__ flags,   // [16][8] step flags
                    unsigned*    __restrict__ xcds)    // [128] XCC ids
{
    const int wg  = blockIdx.x;
    const int bbq = wg & 15;
    const int jb  = wg >> 4;
    const int tid = threadIdx.x;
    const int w   = tid >> 6;
    const int l   = tid & 63;
    const int l15 = l & 15;
    const int lhi = l >> 4;
    const int p   = w >> 1;
    const int kh  = w & 1;
    const int kb0 = kh ? 2 : 0;

    __shared__ __align__(16) char    hstage_raw[16 * ROWB];  // 33 KB padded tile
    __shared__ __align__(16) floatx4 red[2 * 4 * 64];        // 8 KB pair exchange
    __shared__ __align__(16) float   x_lds[16];
    __shared__ __align__(16) float   y_red[4 * 16];
    __shared__            int        fastflag;

    unsigned xcc;
    asm volatile("s_getreg_b32 %0, hwreg(HW_REG_XCC_ID)" : "=s"(xcc));

    // ---- one-time: W_hh A-frags. block b: rows jb*128+p*64+b*16+l15,
    //      k = kh*512 + t*32 + lhi*8  (f16, 256 VGPRs) ----
    half8 wfrag[4][16];
    #pragma unroll
    for (int b = 0; b < 4; ++b) {
        const float* wr = W_hh + (size_t)(jb * 128 + p * 64 + b * 16 + l15) * HH
                         + kh * 512 + lhi * 8;
        #pragma unroll
        for (int t = 0; t < 16; ++t) {
            floatx4 lo = *(const floatx4*)(wr + t * 32);
            floatx4 hi = *(const floatx4*)(wr + t * 32 + 4);
            half8 f;
            f[0]=(_Float16)lo[0]; f[1]=(_Float16)lo[1]; f[2]=(_Float16)lo[2]; f[3]=(_Float16)lo[3];
            f[4]=(_Float16)hi[0]; f[5]=(_Float16)hi[1]; f[6]=(_Float16)hi[2]; f[7]=(_Float16)hi[3];
            wfrag[b][t] = f;
        }
    }

    // per-lane epilogue constants for the 2 KEPT blocks
    float bias_r[2][4], wih_r[2][4], wout_r[2][4];
    #pragma unroll
    for (int b2 = 0; b2 < 2; ++b2)
        #pragma unroll
        for (int r = 0; r < 4; ++r) {
            const int j = jb * 128 + p * 64 + (kb0 + b2) * 16 + lhi * 4 + r;
            bias_r[b2][r] = b_ih[j] + b_hh[j];
            wih_r[b2][r]  = W_ih[j];
            wout_r[b2][r] = W_out[j];
        }
    const float bout = (jb == 0) ? b_out[0] : 0.f;

    // ---- init: fp32 hidden -> f16 hbuf0 (agent stores) + publish XCC id ----
    #pragma unroll
    for (int c = 0; c < 2; ++c) {
        const int q   = tid + c * 256;
        const int row = q >> 5, cc = q & 31;
        const float* s = hidden0 + (size_t)(bbq * 16 + row) * HH + jb * 128 + cc * 4;
        floatx4 f4 = *(const floatx4*)s;
        half4 h4;
        h4[0]=(_Float16)f4[0]; h4[1]=(_Float16)f4[1]; h4[2]=(_Float16)f4[2]; h4[3]=(_Float16)f4[3];
        hstore(hbuf0 + (size_t)(bbq * 16 + row) * HH + jb * 128 + cc * 4,
               __builtin_bit_cast(u64, h4));
    }
    if (tid == 0)
        __hip_atomic_store(&xcds[wg], xcc, __ATOMIC_RELAXED, __HIP_MEMORY_SCOPE_AGENT);
    asm volatile("s_waitcnt vmcnt(0)" ::: "memory");
    __syncthreads();
    if (tid == 0)
        __hip_atomic_fetch_add(&cnt[bbq], 1u, __ATOMIC_RELAXED, __HIP_MEMORY_SCOPE_AGENT);

    // ---- verdict: all 8 group members on one XCD? ----
    if (tid == 0) {
        while (__hip_atomic_load(&cnt[bbq], __ATOMIC_RELAXED,
                                 __HIP_MEMORY_SCOPE_AGENT) < 8u) {}
    }
    __syncthreads();
    if (tid < 64) {
        unsigned v = 0;
        if (l < 8)
            v = __hip_atomic_load(&xcds[(l << 4) + bbq], __ATOMIC_RELAXED,
                                  __HIP_MEMORY_SCOPE_AGENT);
        const unsigned v0 = __shfl(v, 0);
        const bool ok = (l >= 8) || (v == v0);
        const unsigned long long m = __ballot(ok);
        if (tid == 0) fastflag = (m == ~0ull) ? 1 : 0;
    }
    __syncthreads();
    const bool fast = (fastflag != 0);

    if (fast)
        run_steps<true >(bbq, jb, tid, w, l15, lhi, x0, targets, out,
                         hbuf0, hbuf1, cnt, flags, wfrag,
                         bias_r, wih_r, wout_r, bout, x_lds, red, y_red, hstage_raw);
    else
        run_steps<false>(bbq, jb, tid, w, l15, lhi, x0, targets, out,
                         hbuf0, hbuf1, cnt, flags, wfrag,
                         bias_r, wih_r, wout_r, bout, x_lds, red, y_red, hstage_raw);
}

extern "C" void kernel_launch(void* const* d_in, const int* in_sizes, int n_in,
                              void* d_out, int out_size, void* d_ws, size_t ws_size,
                              hipStream_t stream)
{
    const float* x0      = (const float*)d_in[0];
    const float* hidden0 = (const float*)d_in[1];
    const float* targets = (const float*)d_in[2];
    const float* W_ih    = (const float*)d_in[3];
    const float* W_hh    = (const float*)d_in[4];
    const float* b_ih    = (const float*)d_in[5];
    const float* b_hh    = (const float*)d_in[6];
    const float* W_out   = (const float*)d_in[7];
    const float* b_out   = (const float*)d_in[8];
    float* out = (float*)d_out;

    char* ws = (char*)d_ws;
    unsigned* cnt   = (unsigned*)ws;                          // [16]     @0
    unsigned* flags = (unsigned*)(ws + 256);                  // [16][8]  @256
    unsigned* xcds  = (unsigned*)(ws + 1024);                 // [128]    @1024
    _Float16* hbuf0 = (_Float16*)(ws + 4096);                 // 512 KB
    _Float16* hbuf1 = (_Float16*)(ws + 4096 + 512 * 1024);    // 512 KB

    hipMemsetAsync(ws, 0, 4096, stream);
    hipMemsetAsync(d_out, 0, (size_t)out_size * sizeof(float), stream);

    rnn_persistent<<<128, 256, 0, stream>>>(x0, hidden0, targets, W_ih, W_hh,
                                            b_ih, b_hh, W_out, b_out,
                                            out, hbuf0, hbuf1, cnt, flags, xcds);
}